// Round 4
// baseline (262.855 us; speedup 1.0000x reference)
//
#include <hip/hip_runtime.h>

// DCNv2, fp32 in/out, bf16-MFMA contraction.
// (1) x NCHW -> xT bf16 NHWC, (2) prep: wdA bf16 in MFMA A-frag order + woT fp32,
// (3) offset conv: scalar-weight (SGPR) VALU fp32,
// (4) deform: bilinear sample (bf16 x) -> LDS B-frags -> mfma_f32_16x16x32_bf16.
// ws: xT(bf16) 8.39MB | offs(f32) 4.72MB | wdA(bf16) 73728B | woT(f32) 41472B

#define BATCH 4
#define CIN   64
#define COUT  64
#define HH    128
#define WW    128
#define HWPIX (HH*WW)

typedef __attribute__((ext_vector_type(8))) short short8;   // 8 bf16 (4 VGPRs)
typedef __attribute__((ext_vector_type(4))) float floatx4;  // MFMA C/D

__device__ __forceinline__ unsigned short f2bf(float f) {   // RNE f32->bf16
  unsigned int u = __float_as_uint(f);
  unsigned int r = u + 0x7fffu + ((u >> 16) & 1u);
  return (unsigned short)(r >> 16);
}
__device__ __forceinline__ float lo16f(unsigned int u) { return __uint_as_float(u << 16); }
__device__ __forceinline__ float hi16f(unsigned int u) { return __uint_as_float(u & 0xffff0000u); }

__device__ __forceinline__ unsigned int bilin2(unsigned int u00, unsigned int u01,
                                               unsigned int u10, unsigned int u11,
                                               float w00, float w01, float w10, float w11) {
  float lo = w00 * lo16f(u00) + w01 * lo16f(u01) + w10 * lo16f(u10) + w11 * lo16f(u11);
  float hi = w00 * hi16f(u00) + w01 * hi16f(u01) + w10 * hi16f(u10) + w11 * hi16f(u11);
  return (unsigned int)f2bf(lo) | ((unsigned int)f2bf(hi) << 16);
}

// x fp32 NCHW -> xT bf16 [b][px][cin]
__global__ __launch_bounds__(256) void transpose_x_kernel(const float* __restrict__ x,
                                                          unsigned short* __restrict__ xT) {
  __shared__ float tile[32][33];   // [c_local][p_local]
  int b = blockIdx.z, p0 = blockIdx.x * 32, c0 = blockIdx.y * 32;
  int tx = threadIdx.x, ty = threadIdx.y;        // (32,8)
  const float* xb = x + (size_t)b * CIN * HWPIX;
  unsigned short* xTb = xT + (size_t)b * HWPIX * CIN;
#pragma unroll
  for (int i = 0; i < 4; i++)
    tile[ty + i * 8][tx] = xb[(size_t)(c0 + ty + i * 8) * HWPIX + p0 + tx];
  __syncthreads();
  int wid = ty * 32 + tx;
#pragma unroll
  for (int i = 0; i < 2; i++) {
    int t = wid + i * 256;        // 0..511 = 32 rows * 16 cin-pairs
    int row = t >> 4;
    int cp = t & 15;
    ushort2 v = make_ushort2(f2bf(tile[cp * 2][row]), f2bf(tile[cp * 2 + 1][row]));
    *(ushort2*)&xTb[(size_t)(p0 + row) * CIN + c0 + cp * 2] = v;
  }
}

// wdA[kk][kc][ct][lane][j] bf16 (A-frag order), 36864 entries; woT[(cin*9+tap)][c18] fp32
__global__ __launch_bounds__(256) void prep_weights_kernel(const float* __restrict__ wo,
                                                           const float* __restrict__ wd,
                                                           unsigned short* __restrict__ wdA,
                                                           float* __restrict__ woT) {
  int t = blockIdx.x * 256 + threadIdx.x;
  if (t < 36864) {
    int j = t & 7, lane = (t >> 3) & 63, ct = (t >> 9) & 3, kc = (t >> 11) & 1, kk = t >> 12;
    int cout = ct * 16 + (lane & 15);
    int cin  = kc * 32 + (lane >> 4) * 8 + j;
    wdA[t] = f2bf(wd[(size_t)(cout * CIN + cin) * 9 + kk]);
  }
  int t2 = t - 36864;
  if (t2 >= 0 && t2 < 10368) {
    int c = t2 % 18, jt = t2 / 18;   // jt = cin*9+tap
    woT[jt * 18 + c] = wo[c * 576 + jt];
  }
}

// 3x3 conv, 18 out ch; weights via wave-uniform (scalar) loads, x fp32 NCHW.
__global__ __launch_bounds__(128) void offset_conv_kernel(const float* __restrict__ x,
                                                          const float* __restrict__ woT,
                                                          float* __restrict__ offs) {
  int bid = blockIdx.x;            // 512 = 4b * 128y
  int b = bid >> 7, y = bid & 127;
  int xx = threadIdx.x;
  const float* xb = x + (size_t)b * CIN * HWPIX;

  float acc[18];
#pragma unroll
  for (int c = 0; c < 18; c++) acc[c] = 0.f;

  for (int cin = 0; cin < CIN; cin++) {
    const float* xc = xb + (size_t)cin * HWPIX;
    float xv[3][3];
#pragma unroll
    for (int r = 0; r < 3; r++) {
      int yy = y - 1 + r;
      bool vy = (yy >= 0) && (yy < HH);
      const float* xr = xc + yy * WW;
      xv[r][0] = (vy && xx > 0)      ? xr[xx - 1] : 0.f;
      xv[r][1] = vy                  ? xr[xx]     : 0.f;
      xv[r][2] = (vy && xx < WW - 1) ? xr[xx + 1] : 0.f;
    }
    const float* wr = woT + cin * 9 * 18;   // uniform -> s_load
#pragma unroll
    for (int ki = 0; ki < 3; ki++)
#pragma unroll
      for (int kj = 0; kj < 3; kj++) {
        float s = xv[ki][kj];
        const float* wt = wr + (ki * 3 + kj) * 18;
#pragma unroll
        for (int c = 0; c < 18; c++) acc[c] = fmaf(wt[c], s, acc[c]);
      }
  }
  float* o = offs + (size_t)b * 18 * HWPIX + y * WW + xx;
#pragma unroll
  for (int c = 0; c < 18; c++) o[(size_t)c * HWPIX] = acc[c];
}

// Bilinear sample into LDS B-fragments + MFMA contraction.
// Block: 64 px (b, y, x0..x0+63) x 64 cout, 256 thr = 4 waves.
__global__ __launch_bounds__(256) void deform_gemm_kernel(const unsigned short* __restrict__ xT,
                                                          const float* __restrict__ offs,
                                                          const unsigned short* __restrict__ wdA,
                                                          float* __restrict__ out) {
  __shared__ unsigned short sampB[4096];   // [w][kc][lane][j] 8KB, frag-contiguous
  int tid = threadIdx.x;
  int hw = blockIdx.x;
  int bid = (hw & 7) * 128 + (hw >> 3);    // XCD-contiguous y bands
  int b = bid >> 8, r = bid & 255, y = r >> 1, x0 = (r & 1) << 6;

  int p1 = tid >> 2, si = tid & 3;         // phase-1: px, cin-slice (16 cin)
  int lane = tid & 63, w = tid >> 6;       // phase-2: wave id

  const unsigned short* xTb = xT + (size_t)b * HWPIX * CIN;
  const float* ob = offs + (size_t)b * 18 * HWPIX + y * WW + (x0 + p1);

  // phase-1 LDS destinations (ushort indices), two 16B chunks per thread
  int wq = p1 >> 4, iq = p1 & 15;
  int kcd = si >> 1, qb = si & 1;
  int dst0 = (((wq * 2 + kcd) * 64) + qb * 32 + iq) * 8;
  int dst1 = dst0 + 128;

  floatx4 acc[4];
#pragma unroll
  for (int ct = 0; ct < 4; ct++) acc[ct] = (floatx4){0.f, 0.f, 0.f, 0.f};

  int xp = x0 + p1;

#pragma unroll 1
  for (int kk = 0; kk < 9; kk++) {
    // ---- phase 1: sample 16 cin for (px=p1) ----
    {
      float dy = ob[(size_t)(2 * kk) * HWPIX];
      float dx = ob[(size_t)(2 * kk + 1) * HWPIX];
      float ys = (float)(y - 1 + kk / 3) + dy;
      float xs = (float)(xp - 1 + kk % 3) + dx;
      float y0f = floorf(ys), x0f = floorf(xs);
      float wy = ys - y0f, wx = xs - x0f;
      int iy0 = (int)y0f, ix0 = (int)x0f;
      int iy1 = iy0 + 1, ix1 = ix0 + 1;
      float w00 = (1.f - wy) * (1.f - wx), w01 = (1.f - wy) * wx;
      float w10 = wy * (1.f - wx), w11 = wy * wx;
      bool vy0 = (iy0 >= 0) && (iy0 < HH), vy1 = (iy1 >= 0) && (iy1 < HH);
      bool vx0 = (ix0 >= 0) && (ix0 < WW), vx1 = (ix1 >= 0) && (ix1 < WW);
      if (!(vy0 && vx0)) w00 = 0.f;
      if (!(vy0 && vx1)) w01 = 0.f;
      if (!(vy1 && vx0)) w10 = 0.f;
      if (!(vy1 && vx1)) w11 = 0.f;
      int cy0 = min(max(iy0, 0), HH - 1), cy1 = min(max(iy1, 0), HH - 1);
      int cx0 = min(max(ix0, 0), WW - 1), cx1 = min(max(ix1, 0), WW - 1);
      const unsigned short* q00 = xTb + (size_t)(cy0 * WW + cx0) * CIN + si * 16;
      const unsigned short* q01 = xTb + (size_t)(cy0 * WW + cx1) * CIN + si * 16;
      const unsigned short* q10 = xTb + (size_t)(cy1 * WW + cx0) * CIN + si * 16;
      const unsigned short* q11 = xTb + (size_t)(cy1 * WW + cx1) * CIN + si * 16;
      uint4 a00 = *(const uint4*)q00, a01 = *(const uint4*)q01;
      uint4 a10 = *(const uint4*)q10, a11 = *(const uint4*)q11;
      uint4 b00 = *(const uint4*)(q00 + 8), b01 = *(const uint4*)(q01 + 8);
      uint4 b10 = *(const uint4*)(q10 + 8), b11 = *(const uint4*)(q11 + 8);
      uint4 o0, o1;
      o0.x = bilin2(a00.x, a01.x, a10.x, a11.x, w00, w01, w10, w11);
      o0.y = bilin2(a00.y, a01.y, a10.y, a11.y, w00, w01, w10, w11);
      o0.z = bilin2(a00.z, a01.z, a10.z, a11.z, w00, w01, w10, w11);
      o0.w = bilin2(a00.w, a01.w, a10.w, a11.w, w00, w01, w10, w11);
      o1.x = bilin2(b00.x, b01.x, b10.x, b11.x, w00, w01, w10, w11);
      o1.y = bilin2(b00.y, b01.y, b10.y, b11.y, w00, w01, w10, w11);
      o1.z = bilin2(b00.z, b01.z, b10.z, b11.z, w00, w01, w10, w11);
      o1.w = bilin2(b00.w, b01.w, b10.w, b11.w, w00, w01, w10, w11);
      *(uint4*)&sampB[dst0] = o0;
      *(uint4*)&sampB[dst1] = o1;
    }
    __syncthreads();
    // ---- phase 2: MFMA ----
    {
      short8 bv0 = *(const short8*)&sampB[(w * 2 + 0) * 512 + lane * 8];
      short8 bv1 = *(const short8*)&sampB[(w * 2 + 1) * 512 + lane * 8];
      const short8* Ap = (const short8*)(wdA + (size_t)kk * 4096);
#pragma unroll
      for (int ct = 0; ct < 4; ct++) {
        short8 a0 = Ap[ct * 64 + lane];
        short8 a1 = Ap[256 + ct * 64 + lane];
        acc[ct] = __builtin_amdgcn_mfma_f32_16x16x32_bf16(a0, bv0, acc[ct], 0, 0, 0);
        acc[ct] = __builtin_amdgcn_mfma_f32_16x16x32_bf16(a1, bv1, acc[ct], 0, 0, 0);
      }
    }
    __syncthreads();
  }

  // D: col = lane&15 (px in wave tile), row = (lane>>4)*4 + reg (cout in ct tile)
  int px = x0 + w * 16 + (lane & 15);
  int rowb = (lane >> 4) * 4;
  float* outb = out + (size_t)b * COUT * HWPIX + y * WW + px;
#pragma unroll
  for (int ct = 0; ct < 4; ct++)
#pragma unroll
    for (int rr = 0; rr < 4; rr++)
      outb[(size_t)(ct * 16 + rowb + rr) * HWPIX] = acc[ct][rr];
}

extern "C" void kernel_launch(void* const* d_in, const int* in_sizes, int n_in,
                              void* d_out, int out_size, void* d_ws, size_t ws_size,
                              hipStream_t stream) {
  const float* x  = (const float*)d_in[0];
  const float* wo = (const float*)d_in[1];
  const float* wd = (const float*)d_in[2];
  float* out = (float*)d_out;

  char* wsb = (char*)d_ws;
  unsigned short* xT  = (unsigned short*)wsb;                       // 8,388,608 B
  float* offs         = (float*)(wsb + 8388608);                    // 4,718,592 B
  unsigned short* wdA = (unsigned short*)(wsb + 8388608 + 4718592); // 73,728 B
  float* woT          = (float*)(wsb + 8388608 + 4718592 + 73728);  // 41,472 B

  transpose_x_kernel<<<dim3(HWPIX / 32, CIN / 32, BATCH), dim3(32, 8, 1), 0, stream>>>(x, xT);
  prep_weights_kernel<<<dim3(185), dim3(256), 0, stream>>>(wo, wd, wdA, woT);
  offset_conv_kernel<<<dim3(BATCH * HH), dim3(128), 0, stream>>>(x, woT, offs);
  deform_gemm_kernel<<<dim3(BATCH * HWPIX / 64), dim3(256), 0, stream>>>(xT, offs, wdA, out);
}

// Round 5
// 122.248 us; speedup vs baseline: 2.1502x; 2.1502x over previous
//
#include <hip/hip_runtime.h>

// DCNv2, fp32 in/out, all matmul-shaped work on bf16 MFMA.
// (1) x NCHW -> xT_hi/xT_lo bf16 NHWC (split-bf16 of fp32),
// (2) prep: wd A-frags (bf16) + wo split A-frags (hi/lo, M padded 18->32),
// (3) offset conv = im2col GEMM on MFMA, 3-term split-bf16 (fp32-accurate),
// (4) deform: bilinear sample (bf16 hi) -> LDS B-frags -> mfma 16x16x32.
// ws: xThi 8388608 | xTlo 8388608 | offs 4718592 | wdA 73728 | woAhi 36864 | woAlo 36864

#define BATCH 4
#define CIN   64
#define COUT  64
#define HH    128
#define WW    128
#define HWPIX (HH*WW)

typedef __attribute__((ext_vector_type(8))) short short8;   // 8 bf16 (4 VGPRs)
typedef __attribute__((ext_vector_type(4))) float floatx4;  // MFMA C/D

__device__ __forceinline__ unsigned short f2bf(float f) {   // RNE f32->bf16
  unsigned int u = __float_as_uint(f);
  unsigned int r = u + 0x7fffu + ((u >> 16) & 1u);
  return (unsigned short)(r >> 16);
}
__device__ __forceinline__ float bf2f(unsigned short h) { return __uint_as_float(((unsigned int)h) << 16); }
__device__ __forceinline__ float lo16f(unsigned int u) { return __uint_as_float(u << 16); }
__device__ __forceinline__ float hi16f(unsigned int u) { return __uint_as_float(u & 0xffff0000u); }

__device__ __forceinline__ unsigned int bilin2(unsigned int u00, unsigned int u01,
                                               unsigned int u10, unsigned int u11,
                                               float w00, float w01, float w10, float w11) {
  float lo = w00 * lo16f(u00) + w01 * lo16f(u01) + w10 * lo16f(u10) + w11 * lo16f(u11);
  float hi = w00 * hi16f(u00) + w01 * hi16f(u01) + w10 * hi16f(u10) + w11 * hi16f(u11);
  return (unsigned int)f2bf(lo) | ((unsigned int)f2bf(hi) << 16);
}

// x fp32 NCHW -> xThi/xTlo bf16 [b][px][cin]
__global__ __launch_bounds__(256) void transpose_x_kernel(const float* __restrict__ x,
                                                          unsigned short* __restrict__ xThi,
                                                          unsigned short* __restrict__ xTlo) {
  __shared__ float tile[32][33];   // [c_local][p_local]
  int b = blockIdx.z, p0 = blockIdx.x * 32, c0 = blockIdx.y * 32;
  int tx = threadIdx.x, ty = threadIdx.y;        // (32,8)
  const float* xb = x + (size_t)b * CIN * HWPIX;
  size_t boff = (size_t)b * HWPIX * CIN;
#pragma unroll
  for (int i = 0; i < 4; i++)
    tile[ty + i * 8][tx] = xb[(size_t)(c0 + ty + i * 8) * HWPIX + p0 + tx];
  __syncthreads();
  int wid = ty * 32 + tx;
#pragma unroll
  for (int i = 0; i < 2; i++) {
    int t = wid + i * 256;        // 0..511 = 32 rows * 16 cin-pairs
    int row = t >> 4;
    int cp = t & 15;
    float v0 = tile[cp * 2][row], v1 = tile[cp * 2 + 1][row];
    unsigned short h0 = f2bf(v0), h1 = f2bf(v1);
    unsigned short l0 = f2bf(v0 - bf2f(h0)), l1 = f2bf(v1 - bf2f(h1));
    size_t o = boff + (size_t)(p0 + row) * CIN + c0 + cp * 2;
    *(ushort2*)&xThi[o] = make_ushort2(h0, h1);
    *(ushort2*)&xTlo[o] = make_ushort2(l0, l1);
  }
}

// wdA[kk][kc2][ct4][lane][j] bf16 (A-frag, 36864);
// woAhi/lo[kk][kc2][ct2][lane][j] bf16 (A-frag, M=32 rows, rows>=18 zero; 18432 each)
__global__ __launch_bounds__(256) void prep_weights_kernel(const float* __restrict__ wo,
                                                           const float* __restrict__ wd,
                                                           unsigned short* __restrict__ wdA,
                                                           unsigned short* __restrict__ woAhi,
                                                           unsigned short* __restrict__ woAlo) {
  int t = blockIdx.x * 256 + threadIdx.x;
  if (t < 36864) {
    int j = t & 7, lane = (t >> 3) & 63, ct = (t >> 9) & 3, kc = (t >> 11) & 1, kk = t >> 12;
    int cout = ct * 16 + (lane & 15);
    int cin  = kc * 32 + (lane >> 4) * 8 + j;
    wdA[t] = f2bf(wd[(size_t)(cout * CIN + cin) * 9 + kk]);
  }
  int t2 = t - 36864;
  if (t2 >= 0 && t2 < 18432) {
    int j = t2 & 7, lane = (t2 >> 3) & 63, ct = (t2 >> 9) & 1, kc = (t2 >> 10) & 1, kk = t2 >> 11;
    int cout = ct * 16 + (lane & 15);          // conv channel 0..31 (valid < 18)
    int cin  = kc * 32 + (lane >> 4) * 8 + j;
    float v = (cout < 18) ? wo[(size_t)(cout * CIN + cin) * 9 + kk] : 0.f;
    unsigned short h = f2bf(v);
    woAhi[t2] = h;
    woAlo[t2] = f2bf(v - bf2f(h));
  }
}

// Offset conv as im2col GEMM on MFMA, split-bf16 3-term (fp32-accurate).
// Block: 64 px x 32 couts (18 valid), 256 thr = 4 waves x 16 px.
__global__ __launch_bounds__(256) void offset_mfma_kernel(const unsigned short* __restrict__ xThi,
                                                          const unsigned short* __restrict__ xTlo,
                                                          const unsigned short* __restrict__ woAhi,
                                                          const unsigned short* __restrict__ woAlo,
                                                          float* __restrict__ offs) {
  __shared__ unsigned short sBhi[4096];
  __shared__ unsigned short sBlo[4096];
  int tid = threadIdx.x;
  int hw = blockIdx.x;
  int bid = (hw & 7) * 128 + (hw >> 3);
  int b = bid >> 8, r = bid & 255, y = r >> 1, x0 = (r & 1) << 6;

  int p1 = tid >> 2, si = tid & 3;
  int lane = tid & 63, w = tid >> 6;

  const unsigned short* xhib = xThi + (size_t)b * HWPIX * CIN;
  const unsigned short* xlob = xTlo + (size_t)b * HWPIX * CIN;

  int wq = p1 >> 4, iq = p1 & 15;
  int kcd = si >> 1, qb = si & 1;
  int dst0 = (((wq * 2 + kcd) * 64) + qb * 32 + iq) * 8;
  int dst1 = dst0 + 128;

  floatx4 acc[2];
  acc[0] = (floatx4){0.f, 0.f, 0.f, 0.f};
  acc[1] = (floatx4){0.f, 0.f, 0.f, 0.f};

  int xp = x0 + p1;

#pragma unroll 1
  for (int kk = 0; kk < 9; kk++) {
    int ys = y - 1 + kk / 3;
    int xs = xp - 1 + kk % 3;
    bool valid = (ys >= 0) && (ys < HH) && (xs >= 0) && (xs < WW);
    uint4 h0 = {0, 0, 0, 0}, h1 = {0, 0, 0, 0}, l0 = {0, 0, 0, 0}, l1 = {0, 0, 0, 0};
    if (valid) {
      const unsigned short* ph = xhib + (size_t)(ys * WW + xs) * CIN + si * 16;
      const unsigned short* pl = xlob + (size_t)(ys * WW + xs) * CIN + si * 16;
      h0 = *(const uint4*)ph; h1 = *(const uint4*)(ph + 8);
      l0 = *(const uint4*)pl; l1 = *(const uint4*)(pl + 8);
    }
    *(uint4*)&sBhi[dst0] = h0; *(uint4*)&sBhi[dst1] = h1;
    *(uint4*)&sBlo[dst0] = l0; *(uint4*)&sBlo[dst1] = l1;
    __syncthreads();
    short8 bh0 = *(const short8*)&sBhi[(w * 2 + 0) * 512 + lane * 8];
    short8 bh1 = *(const short8*)&sBhi[(w * 2 + 1) * 512 + lane * 8];
    short8 bl0 = *(const short8*)&sBlo[(w * 2 + 0) * 512 + lane * 8];
    short8 bl1 = *(const short8*)&sBlo[(w * 2 + 1) * 512 + lane * 8];
    const short8* Ah = (const short8*)(woAhi + (size_t)kk * 2048);
    const short8* Al = (const short8*)(woAlo + (size_t)kk * 2048);
#pragma unroll
    for (int ct = 0; ct < 2; ct++) {
      short8 ah0 = Ah[ct * 64 + lane], ah1 = Ah[128 + ct * 64 + lane];
      short8 al0 = Al[ct * 64 + lane], al1 = Al[128 + ct * 64 + lane];
      acc[ct] = __builtin_amdgcn_mfma_f32_16x16x32_bf16(ah0, bh0, acc[ct], 0, 0, 0);
      acc[ct] = __builtin_amdgcn_mfma_f32_16x16x32_bf16(ah0, bl0, acc[ct], 0, 0, 0);
      acc[ct] = __builtin_amdgcn_mfma_f32_16x16x32_bf16(al0, bh0, acc[ct], 0, 0, 0);
      acc[ct] = __builtin_amdgcn_mfma_f32_16x16x32_bf16(ah1, bh1, acc[ct], 0, 0, 0);
      acc[ct] = __builtin_amdgcn_mfma_f32_16x16x32_bf16(ah1, bl1, acc[ct], 0, 0, 0);
      acc[ct] = __builtin_amdgcn_mfma_f32_16x16x32_bf16(al1, bh1, acc[ct], 0, 0, 0);
    }
    __syncthreads();
  }

  int px = x0 + w * 16 + (lane & 15);
  int rowb = (lane >> 4) * 4;
  float* ob = offs + (size_t)b * 18 * HWPIX + y * WW + px;
#pragma unroll
  for (int ct = 0; ct < 2; ct++)
#pragma unroll
    for (int rr = 0; rr < 4; rr++) {
      int row = ct * 16 + rowb + rr;
      if (row < 18) ob[(size_t)row * HWPIX] = acc[ct][rr];
    }
}

// Bilinear sample into LDS B-fragments + MFMA contraction.
// Block: 64 px (b, y, x0..x0+63) x 64 cout, 256 thr = 4 waves.
__global__ __launch_bounds__(256) void deform_gemm_kernel(const unsigned short* __restrict__ xT,
                                                          const float* __restrict__ offs,
                                                          const unsigned short* __restrict__ wdA,
                                                          float* __restrict__ out) {
  __shared__ unsigned short sampB[4096];   // [w][kc][lane][j] 8KB, frag-contiguous
  int tid = threadIdx.x;
  int hw = blockIdx.x;
  int bid = (hw & 7) * 128 + (hw >> 3);    // XCD-contiguous y bands
  int b = bid >> 8, r = bid & 255, y = r >> 1, x0 = (r & 1) << 6;

  int p1 = tid >> 2, si = tid & 3;         // phase-1: px, cin-slice (16 cin)
  int lane = tid & 63, w = tid >> 6;       // phase-2: wave id

  const unsigned short* xTb = xT + (size_t)b * HWPIX * CIN;
  const float* ob = offs + (size_t)b * 18 * HWPIX + y * WW + (x0 + p1);

  int wq = p1 >> 4, iq = p1 & 15;
  int kcd = si >> 1, qb = si & 1;
  int dst0 = (((wq * 2 + kcd) * 64) + qb * 32 + iq) * 8;
  int dst1 = dst0 + 128;

  floatx4 acc[4];
#pragma unroll
  for (int ct = 0; ct < 4; ct++) acc[ct] = (floatx4){0.f, 0.f, 0.f, 0.f};

  int xp = x0 + p1;

#pragma unroll 1
  for (int kk = 0; kk < 9; kk++) {
    // ---- phase 1: sample 16 cin for (px=p1) ----
    {
      float dy = ob[(size_t)(2 * kk) * HWPIX];
      float dx = ob[(size_t)(2 * kk + 1) * HWPIX];
      float ys = (float)(y - 1 + kk / 3) + dy;
      float xs = (float)(xp - 1 + kk % 3) + dx;
      float y0f = floorf(ys), x0f = floorf(xs);
      float wy = ys - y0f, wx = xs - x0f;
      int iy0 = (int)y0f, ix0 = (int)x0f;
      int iy1 = iy0 + 1, ix1 = ix0 + 1;
      float w00 = (1.f - wy) * (1.f - wx), w01 = (1.f - wy) * wx;
      float w10 = wy * (1.f - wx), w11 = wy * wx;
      bool vy0 = (iy0 >= 0) && (iy0 < HH), vy1 = (iy1 >= 0) && (iy1 < HH);
      bool vx0 = (ix0 >= 0) && (ix0 < WW), vx1 = (ix1 >= 0) && (ix1 < WW);
      if (!(vy0 && vx0)) w00 = 0.f;
      if (!(vy0 && vx1)) w01 = 0.f;
      if (!(vy1 && vx0)) w10 = 0.f;
      if (!(vy1 && vx1)) w11 = 0.f;
      int cy0 = min(max(iy0, 0), HH - 1), cy1 = min(max(iy1, 0), HH - 1);
      int cx0 = min(max(ix0, 0), WW - 1), cx1 = min(max(ix1, 0), WW - 1);
      const unsigned short* q00 = xTb + (size_t)(cy0 * WW + cx0) * CIN + si * 16;
      const unsigned short* q01 = xTb + (size_t)(cy0 * WW + cx1) * CIN + si * 16;
      const unsigned short* q10 = xTb + (size_t)(cy1 * WW + cx0) * CIN + si * 16;
      const unsigned short* q11 = xTb + (size_t)(cy1 * WW + cx1) * CIN + si * 16;
      uint4 a00 = *(const uint4*)q00, a01 = *(const uint4*)q01;
      uint4 a10 = *(const uint4*)q10, a11 = *(const uint4*)q11;
      uint4 b00 = *(const uint4*)(q00 + 8), b01 = *(const uint4*)(q01 + 8);
      uint4 b10 = *(const uint4*)(q10 + 8), b11 = *(const uint4*)(q11 + 8);
      uint4 o0, o1;
      o0.x = bilin2(a00.x, a01.x, a10.x, a11.x, w00, w01, w10, w11);
      o0.y = bilin2(a00.y, a01.y, a10.y, a11.y, w00, w01, w10, w11);
      o0.z = bilin2(a00.z, a01.z, a10.z, a11.z, w00, w01, w10, w11);
      o0.w = bilin2(a00.w, a01.w, a10.w, a11.w, w00, w01, w10, w11);
      o1.x = bilin2(b00.x, b01.x, b10.x, b11.x, w00, w01, w10, w11);
      o1.y = bilin2(b00.y, b01.y, b10.y, b11.y, w00, w01, w10, w11);
      o1.z = bilin2(b00.z, b01.z, b10.z, b11.z, w00, w01, w10, w11);
      o1.w = bilin2(b00.w, b01.w, b10.w, b11.w, w00, w01, w10, w11);
      *(uint4*)&sampB[dst0] = o0;
      *(uint4*)&sampB[dst1] = o1;
    }
    __syncthreads();
    // ---- phase 2: MFMA ----
    {
      short8 bv0 = *(const short8*)&sampB[(w * 2 + 0) * 512 + lane * 8];
      short8 bv1 = *(const short8*)&sampB[(w * 2 + 1) * 512 + lane * 8];
      const short8* Ap = (const short8*)(wdA + (size_t)kk * 4096);
#pragma unroll
      for (int ct = 0; ct < 4; ct++) {
        short8 a0 = Ap[ct * 64 + lane];
        short8 a1 = Ap[256 + ct * 64 + lane];
        acc[ct] = __builtin_amdgcn_mfma_f32_16x16x32_bf16(a0, bv0, acc[ct], 0, 0, 0);
        acc[ct] = __builtin_amdgcn_mfma_f32_16x16x32_bf16(a1, bv1, acc[ct], 0, 0, 0);
      }
    }
    __syncthreads();
  }

  // D: col = lane&15 (px in wave tile), row = (lane>>4)*4 + reg (cout in ct tile)
  int px = x0 + w * 16 + (lane & 15);
  int rowb = (lane >> 4) * 4;
  float* outb = out + (size_t)b * COUT * HWPIX + y * WW + px;
#pragma unroll
  for (int ct = 0; ct < 4; ct++)
#pragma unroll
    for (int rr = 0; rr < 4; rr++)
      outb[(size_t)(ct * 16 + rowb + rr) * HWPIX] = acc[ct][rr];
}

extern "C" void kernel_launch(void* const* d_in, const int* in_sizes, int n_in,
                              void* d_out, int out_size, void* d_ws, size_t ws_size,
                              hipStream_t stream) {
  const float* x  = (const float*)d_in[0];
  const float* wo = (const float*)d_in[1];
  const float* wd = (const float*)d_in[2];
  float* out = (float*)d_out;

  char* wsb = (char*)d_ws;
  unsigned short* xThi  = (unsigned short*)wsb;                         // 8,388,608 B
  unsigned short* xTlo  = (unsigned short*)(wsb + 8388608);             // 8,388,608 B
  float* offs           = (float*)(wsb + 16777216);                     // 4,718,592 B
  unsigned short* wdA   = (unsigned short*)(wsb + 16777216 + 4718592);  // 73,728 B
  unsigned short* woAhi = (unsigned short*)(wsb + 21495808 + 73728);    // 36,864 B
  unsigned short* woAlo = (unsigned short*)(wsb + 21569536 + 36864);    // 36,864 B

  transpose_x_kernel<<<dim3(HWPIX / 32, CIN / 32, BATCH), dim3(32, 8, 1), 0, stream>>>(x, xThi, xTlo);
  prep_weights_kernel<<<dim3(216), dim3(256), 0, stream>>>(wo, wd, wdA, woAhi, woAlo);
  offset_mfma_kernel<<<dim3(BATCH * HWPIX / 64), dim3(256), 0, stream>>>(xThi, xTlo, woAhi, woAlo, offs);
  deform_gemm_kernel<<<dim3(BATCH * HWPIX / 64), dim3(256), 0, stream>>>(xThi, offs, wdA, out);
}